// Round 8
// baseline (338.701 us; speedup 1.0000x reference)
//
#include <hip/hip_runtime.h>
#include <cstdint>
#include <cstddef>

#define B_    4096
#define H_    1024
#define NOBS  128
#define NDIR  64
#define MAXIT 10
#define LRI   1e-3f
#define TOLC  1e-3
#define KS_   8      // split-K factor for logits GEMM

typedef _Float16 f16x8 __attribute__((ext_vector_type(8)));
typedef float    f32x4 __attribute__((ext_vector_type(4)));

static __device__ __forceinline__ ushort f2h(float x) {
    _Float16 h = (_Float16)x;                 // RN-even
    return __builtin_bit_cast(ushort, h);
}

// gate: active iff all tested conds so far exceeded tol. slots[j] holds
// sum(prev_j) - sum(cur_j); |mean| > 1e-3  <=>  |slot| > 1e-3*B*H.
static __device__ __forceinline__ bool gate_on(const double* slots, int it) {
    if (it < 0) return true;                  // ungated launch
    const double GTH = 1e-3 * (double)B_ * (double)H_;
    for (int j = 0; j <= it; ++j)
        if (fabs(slots[j]) <= GTH) return false;
    return true;
}

// ---------------------------------------------------------------------------
// Stage one ROWSx32 f16 tile into LDS via global_load_lds (16B/lane),
// XOR-swizzled global source; LDS linear; reads apply the same XOR.
// ---------------------------------------------------------------------------
template<int ROWS>
__device__ __forceinline__ void stage_tile(ushort* dst, const ushort* src,
                                           size_t rowbase, int ld, int k0,
                                           int tid, int wid)
{
    constexpr int ITERS = ROWS * 4 / 256;
#pragma unroll
    for (int cc = 0; cc < ITERS; ++cc) {
        const int c = cc * 256 + tid;
        const int r = c >> 2, s = c & 3;
        const int ks = ((s ^ ((r >> 1) & 3)) << 3);
        const ushort* g = src + (rowbase + r) * (size_t)ld + k0 + ks;
        __builtin_amdgcn_global_load_lds(
            (const __attribute__((address_space(1))) void*)g,
            (__attribute__((address_space(3))) void*)(dst + (cc * 256 + wid * 64) * 8),
            16, 0, 0);
    }
}

// ---------------------------------------------------------------------------
// Unified f16 MFMA GEMM: O[m,n] = sum_k A[m,k] * Bt[n,k].
// BM=64 rows, BN cols, BK=32, 4 waves (2x2); wave tile 32 x BN/2;
// frags: 2 x (BN/32) of 16x16x32. Double-buffered, __syncthreads drain
// (proven race-free); grid big enough for 2-4 blocks/CU.
// EPI 0: O = relu(acc + Win[col, dirs[row]])   (Wr GEMM,  grid 16x64)
// EPI 1: part[bx] = acc                        (logits split-K, grid 8x64)
// EPI 2: O = Cin + LRI*((O - Cin) + acc)       (update GEMM, grid 16x64)
// ---------------------------------------------------------------------------
template<int EPI, int BN>
__global__ __launch_bounds__(256)
void gemm_f16_k(const ushort* __restrict__ A, int lda,
                const ushort* __restrict__ Bt, int ldb,
                float* __restrict__ O,
                const int* __restrict__ dirs, const float* __restrict__ Win,
                const float* __restrict__ Cin,
                const double* __restrict__ slots, int it)
{
    if (!gate_on(slots, it)) return;

    constexpr int FN  = BN / 32;              // N frags per wave
    constexpr int NST = (EPI == 0) ? H_ / 32
                      : (EPI == 1) ? (H_ / KS_) / 32
                                   : NOBS / 32;

    __shared__ ushort sA[2][64 * 32];
    __shared__ ushort sB[2][BN * 32];

    const int tid = threadIdx.x, lane = tid & 63, wid = tid >> 6;
    const size_t m0  = (size_t)blockIdx.y * 64;
    const size_t bn0 = (EPI == 1) ? 0 : (size_t)blockIdx.x * BN;
    const int kbase  = (EPI == 1) ? blockIdx.x * (H_ / KS_) : 0;
    const int wr = wid >> 1, wc = wid & 1;

    f32x4 acc[2][FN];
#pragma unroll
    for (int i = 0; i < 2; ++i)
#pragma unroll
        for (int j = 0; j < FN; ++j) acc[i][j] = (f32x4){0.f, 0.f, 0.f, 0.f};

    const int rsel = lane & 15;
    const int kb   = lane >> 4;

    stage_tile<64>(sA[0], A, m0, lda, kbase, tid, wid);
    stage_tile<BN>(sB[0], Bt, bn0, ldb, kbase, tid, wid);
    __syncthreads();

#pragma unroll
    for (int t = 0; t < NST; ++t) {
        const int cur = t & 1;
        if (t + 1 < NST) {
            const int k0 = kbase + (t + 1) * 32;
            stage_tile<64>(sA[cur ^ 1], A, m0, lda, k0, tid, wid);
            stage_tile<BN>(sB[cur ^ 1], Bt, bn0, ldb, k0, tid, wid);
        }

        f16x8 a[2], b[FN];
#pragma unroll
        for (int fi = 0; fi < 2; ++fi) {
            const int arow = wr * 32 + fi * 16 + rsel;
            const int aoff = arow * 32 + ((kb ^ ((arow >> 1) & 3)) << 3);
            a[fi] = *(const f16x8*)&sA[cur][aoff];
        }
#pragma unroll
        for (int fj = 0; fj < FN; ++fj) {
            const int brow = wc * (BN / 2) + fj * 16 + rsel;
            const int boff = brow * 32 + ((kb ^ ((brow >> 1) & 3)) << 3);
            b[fj] = *(const f16x8*)&sB[cur][boff];
        }

#pragma unroll
        for (int fi = 0; fi < 2; ++fi)
#pragma unroll
            for (int fj = 0; fj < FN; ++fj)
                acc[fi][fj] = __builtin_amdgcn_mfma_f32_16x16x32_f16(
                    a[fi], b[fj], acc[fi][fj], 0, 0, 0);
        __syncthreads();
    }

    // epilogue: C/D layout col = lane&15, row = (lane>>4)*4 + r
    float* pout = (EPI == 1) ? O + (size_t)blockIdx.x * B_ * NOBS : O;
#pragma unroll
    for (int fi = 0; fi < 2; ++fi) {
#pragma unroll
        for (int r = 0; r < 4; ++r) {
            const size_t row = m0 + wr * 32 + fi * 16 + (lane >> 4) * 4 + r;
            int dd = 0;
            if (EPI == 0) dd = dirs[row];
#pragma unroll
            for (int fj = 0; fj < FN; ++fj) {
                const size_t col = bn0 + wc * (BN / 2) + fj * 16 + (lane & 15);
                if (EPI == 0) {
                    const float v = acc[fi][fj][r] + Win[col * NDIR + dd];
                    pout[row * H_ + col] = fmaxf(v, 0.f);
                } else if (EPI == 1) {
                    pout[row * NOBS + col] = acc[fi][fj][r];
                } else {
                    const size_t idx = row * H_ + col;
                    const float c = Cin[idx], rv = pout[idx];
                    pout[idx] = c + LRI * ((rv - c) + acc[fi][fj][r]);
                }
            }
        }
    }
}

// ---------------------------------------------------------------------------
// Reduce split-K partials -> logits; softmax.
// MODE 0: + softmax-Jacobian vector product, write Jv as f16 (gated).
// MODE 1: write probabilities to out (ungated, final).
// ---------------------------------------------------------------------------
template<int MODE>
__global__ __launch_bounds__(256)
void softjv_k(const float* __restrict__ part, const int* __restrict__ obs,
              ushort* __restrict__ Jh, float* __restrict__ probs,
              const double* __restrict__ slots, int it)
{
    if (MODE == 0 && !gate_on(slots, it)) return;
    const int wid = threadIdx.x >> 6, lane = threadIdx.x & 63;
    const int b = blockIdx.x * 4 + wid;
    float x0 = 0.f, x1 = 0.f;
#pragma unroll
    for (int kb = 0; kb < KS_; ++kb) {
        const float* p = part + ((size_t)kb * B_ + b) * NOBS;
        x0 += p[lane]; x1 += p[lane + 64];
    }
    float mx = fmaxf(x0, x1);
#pragma unroll
    for (int off = 32; off > 0; off >>= 1) mx = fmaxf(mx, __shfl_xor(mx, off, 64));
    const float e0 = expf(x0 - mx), e1 = expf(x1 - mx);
    float s = e0 + e1;
#pragma unroll
    for (int off = 32; off > 0; off >>= 1) s += __shfl_xor(s, off, 64);
    const float f0 = e0 / s, f1 = e1 / s;
    if (MODE == 1) {
        probs[(size_t)b * NOBS + lane]      = f0;
        probs[(size_t)b * NOBS + lane + 64] = f1;
        return;
    }
    const int o = obs[b];
    const float ep0 = ((lane == o) ? 1.f : 0.f) - f0;
    const float ep1 = ((lane + 64 == o) ? 1.f : 0.f) - f1;
    float d = f0 * ep0 + f1 * ep1;
#pragma unroll
    for (int off = 32; off > 0; off >>= 1) d += __shfl_xor(d, off, 64);
    Jh[(size_t)b * NOBS + lane]      = f2h(f0 * (ep0 - d));
    Jh[(size_t)b * NOBS + lane + 64] = f2h(f1 * (ep1 - d));
}

// ---------------------------------------------------------------------------
// Fused advance + row-normalize + convergence-slot accumulation.
//   if ADV: P_h <- C_h (prev_{t+1} = cur_t)
//   C <- norm(T); C_h <- f16(C)
//   atomicAdd(slotdst, oldsum[b] - sum(Cnew row)); rowsum[b] <- new sum
// ---------------------------------------------------------------------------
template<bool ADV>
__global__ __launch_bounds__(256)
void normadv_k(const float* __restrict__ T, float* __restrict__ C,
               ushort* __restrict__ C_h, ushort* __restrict__ P_h,
               const float* __restrict__ oldsum, float* __restrict__ rowsum,
               double* __restrict__ slotdst,
               const double* __restrict__ slots, int it)
{
    if (!gate_on(slots, it)) return;
    const int b = blockIdx.x, tid = threadIdx.x;
    const size_t ro = (size_t)b * H_;

    if (ADV)
        ((ushort4*)(P_h + ro))[tid] = ((const ushort4*)(C_h + ro))[tid];

    const float4 v = ((const float4*)(T + ro))[tid];
    float ss = v.x * v.x + v.y * v.y + v.z * v.z + v.w * v.w;
    float sm = v.x + v.y + v.z + v.w;
#pragma unroll
    for (int off = 32; off > 0; off >>= 1) {
        ss += __shfl_down(ss, off, 64);
        sm += __shfl_down(sm, off, 64);
    }
    __shared__ float w1[4], w2[4];
    const int lane = tid & 63, wid = tid >> 6;
    if (lane == 0) { w1[wid] = ss; w2[wid] = sm; }
    __syncthreads();
    const float tot = w1[0] + w1[1] + w1[2] + w1[3];
    const float smt = w2[0] + w2[1] + w2[2] + w2[3];
    const float d = sqrtf(tot) + 1e-6f;

    float4 o;
    o.x = v.x / d; o.y = v.y / d; o.z = v.z / d; o.w = v.w / d;
    ((float4*)(C + ro))[tid] = o;
    ushort4 h;
    h.x = f2h(o.x); h.y = f2h(o.y); h.z = f2h(o.z); h.w = f2h(o.w);
    ((ushort4*)(C_h + ro))[tid] = h;

    if (tid == 0) {
        const float news = smt / d;
        atomicAdd(slotdst, (double)oldsum[b] - (double)news);
        rowsum[b] = news;
    }
}

// prev0 -> f16 + per-row sums; block 0 also zeroes the gate slots.
__global__ __launch_bounds__(256)
void prev0_prep_k(const float* __restrict__ prev0, ushort* __restrict__ P_h,
                  float* __restrict__ prevsum0, double* __restrict__ slots)
{
    const int b = blockIdx.x, tid = threadIdx.x;
    if (b == 0 && tid < 16) slots[tid] = 0.0;
    const size_t ro = (size_t)b * H_;
    const float4 v = ((const float4*)(prev0 + ro))[tid];
    ushort4 h;
    h.x = f2h(v.x); h.y = f2h(v.y); h.z = f2h(v.z); h.w = f2h(v.w);
    ((ushort4*)(P_h + ro))[tid] = h;
    float sm = v.x + v.y + v.z + v.w;
#pragma unroll
    for (int off = 32; off > 0; off >>= 1) sm += __shfl_down(sm, off, 64);
    __shared__ float w2[4];
    const int lane = tid & 63, wid = tid >> 6;
    if (lane == 0) w2[wid] = sm;
    __syncthreads();
    if (tid == 0) prevsum0[b] = w2[0] + w2[1] + w2[2] + w2[3];
}

// Wr -> f16 (blocks 0..1023); Wout -> f16 + transposed f16 (blocks 1024..1535)
__global__ __launch_bounds__(256)
void conv_w_k(const float* __restrict__ Wr, ushort* __restrict__ Wr_h,
              const float* __restrict__ Wout, ushort* __restrict__ W_h,
              ushort* __restrict__ WT_h)
{
    const int bid = blockIdx.x;
    if (bid < 1024) {
        const size_t i = (size_t)bid * 256 + threadIdx.x;
        const float4 v = ((const float4*)Wr)[i];
        ushort4 h;
        h.x = f2h(v.x); h.y = f2h(v.y); h.z = f2h(v.z); h.w = f2h(v.w);
        ((ushort4*)Wr_h)[i] = h;
    } else {
        const int idx = (bid - 1024) * 256 + threadIdx.x;   // < NOBS*H_
        const ushort h = f2h(Wout[idx]);
        W_h[idx] = h;
        const int o = idx >> 10, hh = idx & 1023;
        WT_h[(size_t)hh * NOBS + o] = h;
    }
}

__global__ __launch_bounds__(256)
void copy_k(const float* __restrict__ src, float* __restrict__ dst)
{
    const size_t i = (size_t)blockIdx.x * 256 + threadIdx.x;
    ((float4*)dst)[i] = ((const float4*)src)[i];
}

// ---------------------------------------------------------------------------
extern "C" void kernel_launch(void* const* d_in, const int* in_sizes, int n_in,
                              void* d_out, int out_size, void* d_ws, size_t ws_size,
                              hipStream_t stream)
{
    const int*   dirs  = (const int*)d_in[0];
    const int*   obs   = (const int*)d_in[1];
    const float* Wr    = (const float*)d_in[2];
    const float* Win   = (const float*)d_in[3];
    const float* Wout  = (const float*)d_in[4];
    const float* prev0 = (const float*)d_in[5];
    float* out = (float*)d_out;

    const size_t SZ = (size_t)B_ * H_;
    double* slots    = (double*)d_ws;                       // 16 doubles
    float*  C        = (float*)(slots + 16);
    float*  T        = C + SZ;
    float*  part     = T + SZ;                              // KS_*B_*NOBS
    float*  prevsum0 = part + (size_t)KS_ * B_ * NOBS;
    float*  rowsum   = prevsum0 + B_;
    ushort* Wr_h     = (ushort*)(rowsum + B_);
    ushort* W_h      = Wr_h + (size_t)H_ * H_;
    ushort* WT_h     = W_h + (size_t)NOBS * H_;
    ushort* C_h      = WT_h + (size_t)H_ * NOBS;
    ushort* P_h      = C_h + SZ;
    ushort* J_h      = P_h + SZ;

    const dim3 blk(256);
    const dim3 gBig(H_ / 64, B_ / 64);     // 16 x 64 = 1024 blocks
    const dim3 gLog(KS_, B_ / 64);         //  8 x 64 =  512 blocks

    prev0_prep_k<<<B_, blk, 0, stream>>>(prev0, P_h, prevsum0, slots);
    conv_w_k<<<1024 + 512, blk, 0, stream>>>(Wr, Wr_h, Wout, W_h, WT_h);

    // initial: T = relu(Wr@prev0 + drive); C = norm(T); slot[0]
    gemm_f16_k<0, 64><<<gBig, blk, 0, stream>>>(
        P_h, H_, Wr_h, H_, T, dirs, Win, nullptr, slots, -1);
    normadv_k<false><<<B_, blk, 0, stream>>>(
        T, C, C_h, nullptr, prevsum0, rowsum, slots + 0, slots, -1);

    for (int it = 0; it < MAXIT; ++it) {
        // R = relu(Wr@prev + drive) -> T.  At it==0, T already holds R_0.
        if (it > 0)
            gemm_f16_k<0, 64><<<gBig, blk, 0, stream>>>(
                P_h, H_, Wr_h, H_, T, dirs, Win, nullptr, slots, it);
        // logits split-K partials from cur
        gemm_f16_k<1, 128><<<gLog, blk, 0, stream>>>(
            C_h, H_, W_h, H_, part, nullptr, nullptr, nullptr, slots, it);
        // reduce + softmax + Jv (f16)
        softjv_k<0><<<B_ / 4, blk, 0, stream>>>(part, obs, J_h, nullptr, slots, it);
        // T = C + lr*((T - C) + Jv @ Wout)
        gemm_f16_k<2, 64><<<gBig, blk, 0, stream>>>(
            J_h, NOBS, WT_h, NOBS, T, nullptr, nullptr, C, slots, it);
        // prev <- cur; C <- norm(T); slot[it+1]
        normadv_k<true><<<B_, blk, 0, stream>>>(
            T, C, C_h, P_h, rowsum, rowsum, slots + it + 1, slots, it);
    }

    // outputs: softmax(Wout @ cur), then cur
    gemm_f16_k<1, 128><<<gLog, blk, 0, stream>>>(
        C_h, H_, W_h, H_, part, nullptr, nullptr, nullptr, slots, -1);
    softjv_k<1><<<B_ / 4, blk, 0, stream>>>(part, obs, nullptr, out, slots, -1);
    copy_k<<<SZ / 4 / 256, blk, 0, stream>>>(C, out + (size_t)B_ * NOBS);
}

// Round 10
// 276.602 us; speedup vs baseline: 1.2245x; 1.2245x over previous
//
#include <hip/hip_runtime.h>
#include <cstdint>
#include <cstddef>

#define B_    4096
#define H_    1024
#define NOBS  128
#define NDIR  64
#define MAXIT 10
#define LRI   1e-3f
#define TOLC  1e-3
#define KS_   8      // split-K factor for logits GEMM

typedef _Float16 f16x8 __attribute__((ext_vector_type(8)));
typedef float    f32x4 __attribute__((ext_vector_type(4)));

static __device__ __forceinline__ ushort f2h(float x) {
    _Float16 h = (_Float16)x;                 // RN-even
    return __builtin_bit_cast(ushort, h);
}

// gate: active iff all tested conds so far exceeded tol. slots[j] holds
// sum(prev_j) - sum(cur_j); |mean| > 1e-3  <=>  |slot| > 1e-3*B*H.
static __device__ __forceinline__ bool gate_on(const double* slots, int it) {
    if (it < 0) return true;                  // ungated launch
    const double GTH = 1e-3 * (double)B_ * (double)H_;
    for (int j = 0; j <= it; ++j)
        if (fabs(slots[j]) <= GTH) return false;
    return true;
}

// ---------------------------------------------------------------------------
// Stage one ROWSx32 f16 tile into LDS via global_load_lds (16B/lane),
// XOR-swizzled global source; LDS linear; reads apply the same XOR.
// ---------------------------------------------------------------------------
template<int ROWS>
__device__ __forceinline__ void stage_tile(ushort* dst, const ushort* src,
                                           size_t rowbase, int ld, int k0,
                                           int tid, int wid)
{
    constexpr int ITERS = ROWS * 4 / 256;
#pragma unroll
    for (int cc = 0; cc < ITERS; ++cc) {
        const int c = cc * 256 + tid;
        const int r = c >> 2, s = c & 3;
        const int ks = ((s ^ ((r >> 1) & 3)) << 3);
        const ushort* g = src + (rowbase + r) * (size_t)ld + k0 + ks;
        __builtin_amdgcn_global_load_lds(
            (const __attribute__((address_space(1))) void*)g,
            (__attribute__((address_space(3))) void*)(dst + (cc * 256 + wid * 64) * 8),
            16, 0, 0);
    }
}

// ---------------------------------------------------------------------------
// Unified f16 MFMA GEMM: O[m,n] = sum_k A[m,k] * Bt[n,k].
// BM=64 rows, BN cols, BK=32, 4 waves (2x2); wave tile 32 x BN/2;
// frags: 2 x (BN/32) of 16x16x32. Double-buffered, __syncthreads drain
// (proven race-free); grid big enough for 2-4 blocks/CU.
// EPI 0: O = relu(acc + Win[col, dirs[row]])   (Wr GEMM,  grid 16x64)
// EPI 1: part[bx] = acc                        (logits split-K, grid 8x64)
// EPI 2: O = Cin + LRI*((O - Cin) + acc)       (update GEMM, grid 16x64)
// ---------------------------------------------------------------------------
template<int EPI, int BN>
__global__ __launch_bounds__(256)
void gemm_f16_k(const ushort* __restrict__ A, int lda,
                const ushort* __restrict__ Bt, int ldb,
                float* __restrict__ O,
                const int* __restrict__ dirs, const float* __restrict__ Win,
                const float* __restrict__ Cin,
                const double* __restrict__ slots, int it)
{
    if (!gate_on(slots, it)) return;

    constexpr int FN  = BN / 32;              // N frags per wave
    constexpr int NST = (EPI == 0) ? H_ / 32
                      : (EPI == 1) ? (H_ / KS_) / 32
                                   : NOBS / 32;

    __shared__ ushort sA[2][64 * 32];
    __shared__ ushort sB[2][BN * 32];

    const int tid = threadIdx.x, lane = tid & 63, wid = tid >> 6;
    const size_t m0  = (size_t)blockIdx.y * 64;
    const size_t bn0 = (EPI == 1) ? 0 : (size_t)blockIdx.x * BN;
    const int kbase  = (EPI == 1) ? blockIdx.x * (H_ / KS_) : 0;
    const int wr = wid >> 1, wc = wid & 1;

    f32x4 acc[2][FN];
#pragma unroll
    for (int i = 0; i < 2; ++i)
#pragma unroll
        for (int j = 0; j < FN; ++j) acc[i][j] = (f32x4){0.f, 0.f, 0.f, 0.f};

    const int rsel = lane & 15;
    const int kb   = lane >> 4;

    stage_tile<64>(sA[0], A, m0, lda, kbase, tid, wid);
    stage_tile<BN>(sB[0], Bt, bn0, ldb, kbase, tid, wid);
    __syncthreads();

#pragma unroll
    for (int t = 0; t < NST; ++t) {
        const int cur = t & 1;
        if (t + 1 < NST) {
            const int k0 = kbase + (t + 1) * 32;
            stage_tile<64>(sA[cur ^ 1], A, m0, lda, k0, tid, wid);
            stage_tile<BN>(sB[cur ^ 1], Bt, bn0, ldb, k0, tid, wid);
        }

        f16x8 a[2], b[FN];
#pragma unroll
        for (int fi = 0; fi < 2; ++fi) {
            const int arow = wr * 32 + fi * 16 + rsel;
            const int aoff = arow * 32 + ((kb ^ ((arow >> 1) & 3)) << 3);
            a[fi] = *(const f16x8*)&sA[cur][aoff];
        }
#pragma unroll
        for (int fj = 0; fj < FN; ++fj) {
            const int brow = wc * (BN / 2) + fj * 16 + rsel;
            const int boff = brow * 32 + ((kb ^ ((brow >> 1) & 3)) << 3);
            b[fj] = *(const f16x8*)&sB[cur][boff];
        }

#pragma unroll
        for (int fi = 0; fi < 2; ++fi)
#pragma unroll
            for (int fj = 0; fj < FN; ++fj)
                acc[fi][fj] = __builtin_amdgcn_mfma_f32_16x16x32_f16(
                    a[fi], b[fj], acc[fi][fj], 0, 0, 0);
        __syncthreads();
    }

    // epilogue: C/D layout col = lane&15, row = (lane>>4)*4 + r
    float* pout = (EPI == 1) ? O + (size_t)blockIdx.x * B_ * NOBS : O;
#pragma unroll
    for (int fi = 0; fi < 2; ++fi) {
#pragma unroll
        for (int r = 0; r < 4; ++r) {
            const size_t row = m0 + wr * 32 + fi * 16 + (lane >> 4) * 4 + r;
            int dd = 0;
            if (EPI == 0) dd = dirs[row];
#pragma unroll
            for (int fj = 0; fj < FN; ++fj) {
                const size_t col = bn0 + wc * (BN / 2) + fj * 16 + (lane & 15);
                if (EPI == 0) {
                    const float v = acc[fi][fj][r] + Win[col * NDIR + dd];
                    pout[row * H_ + col] = fmaxf(v, 0.f);
                } else if (EPI == 1) {
                    pout[row * NOBS + col] = acc[fi][fj][r];
                } else {
                    const size_t idx = row * H_ + col;
                    const float c = Cin[idx], rv = pout[idx];
                    pout[idx] = c + LRI * ((rv - c) + acc[fi][fj][r]);
                }
            }
        }
    }
}

// ---------------------------------------------------------------------------
// Reduce split-K partials -> logits; softmax.
// MODE 0: + softmax-Jacobian vector product, write Jv as f16 (gated).
// MODE 1: write probabilities to out (ungated, final).
// ---------------------------------------------------------------------------
template<int MODE>
__global__ __launch_bounds__(256)
void softjv_k(const float* __restrict__ part, const int* __restrict__ obs,
              ushort* __restrict__ Jh, float* __restrict__ probs,
              const double* __restrict__ slots, int it)
{
    if (MODE == 0 && !gate_on(slots, it)) return;
    const int wid = threadIdx.x >> 6, lane = threadIdx.x & 63;
    const int b = blockIdx.x * 4 + wid;
    float x0 = 0.f, x1 = 0.f;
#pragma unroll
    for (int kb = 0; kb < KS_; ++kb) {
        const float* p = part + ((size_t)kb * B_ + b) * NOBS;
        x0 += p[lane]; x1 += p[lane + 64];
    }
    float mx = fmaxf(x0, x1);
#pragma unroll
    for (int off = 32; off > 0; off >>= 1) mx = fmaxf(mx, __shfl_xor(mx, off, 64));
    const float e0 = expf(x0 - mx), e1 = expf(x1 - mx);
    float s = e0 + e1;
#pragma unroll
    for (int off = 32; off > 0; off >>= 1) s += __shfl_xor(s, off, 64);
    const float f0 = e0 / s, f1 = e1 / s;
    if (MODE == 1) {
        probs[(size_t)b * NOBS + lane]      = f0;
        probs[(size_t)b * NOBS + lane + 64] = f1;
        return;
    }
    const int o = obs[b];
    const float ep0 = ((lane == o) ? 1.f : 0.f) - f0;
    const float ep1 = ((lane + 64 == o) ? 1.f : 0.f) - f1;
    float d = f0 * ep0 + f1 * ep1;
#pragma unroll
    for (int off = 32; off > 0; off >>= 1) d += __shfl_xor(d, off, 64);
    Jh[(size_t)b * NOBS + lane]      = f2h(f0 * (ep0 - d));
    Jh[(size_t)b * NOBS + lane + 64] = f2h(f1 * (ep1 - d));
}

// ---------------------------------------------------------------------------
// Fused advance + row-normalize + per-row convergence partial (NO atomics:
// single-address atomicAdd from 4096 blocks serialized at ~14ns -> 56us,
// measured round 8; per-block store + tiny reduce instead).
//   if ADV: P_h <- C_h (prev_{t+1} = cur_t)
//   C <- norm(T); C_h <- f16(C)
//   rowpart[b] <- oldsum[b] - sum(Cnew row); rowsum[b] <- new sum
// ---------------------------------------------------------------------------
template<bool ADV>
__global__ __launch_bounds__(256)
void normadv_k(const float* __restrict__ T, float* __restrict__ C,
               ushort* __restrict__ C_h, ushort* __restrict__ P_h,
               const float* __restrict__ oldsum, float* __restrict__ rowsum,
               double* __restrict__ rowpart,
               const double* __restrict__ slots, int it)
{
    if (!gate_on(slots, it)) return;
    const int b = blockIdx.x, tid = threadIdx.x;
    const size_t ro = (size_t)b * H_;

    if (ADV)
        ((ushort4*)(P_h + ro))[tid] = ((const ushort4*)(C_h + ro))[tid];

    const float4 v = ((const float4*)(T + ro))[tid];
    float ss = v.x * v.x + v.y * v.y + v.z * v.z + v.w * v.w;
    float sm = v.x + v.y + v.z + v.w;
#pragma unroll
    for (int off = 32; off > 0; off >>= 1) {
        ss += __shfl_down(ss, off, 64);
        sm += __shfl_down(sm, off, 64);
    }
    __shared__ float w1[4], w2[4];
    const int lane = tid & 63, wid = tid >> 6;
    if (lane == 0) { w1[wid] = ss; w2[wid] = sm; }
    __syncthreads();
    const float tot = w1[0] + w1[1] + w1[2] + w1[3];
    const float smt = w2[0] + w2[1] + w2[2] + w2[3];
    const float d = sqrtf(tot) + 1e-6f;

    float4 o;
    o.x = v.x / d; o.y = v.y / d; o.z = v.z / d; o.w = v.w / d;
    ((float4*)(C + ro))[tid] = o;
    ushort4 h;
    h.x = f2h(o.x); h.y = f2h(o.y); h.z = f2h(o.z); h.w = f2h(o.w);
    ((ushort4*)(C_h + ro))[tid] = h;

    if (tid == 0) {
        const float news = smt / d;
        rowpart[b] = (double)oldsum[b] - (double)news;
        rowsum[b]  = news;
    }
}

// reduce 4096 row partials -> slots[dst]; deterministic, 1 block. Gated:
// if inactive, slots[dst] stays 0 => all later gates read 0 and stay off.
__global__ __launch_bounds__(256)
void slot_fin_k(const double* __restrict__ rowpart, double* __restrict__ slots,
                int dst, int it)
{
    if (!gate_on(slots, it)) return;
    double s = 0.0;
    for (int i = threadIdx.x; i < B_; i += 256) s += rowpart[i];
#pragma unroll
    for (int off = 32; off > 0; off >>= 1) s += __shfl_down(s, off, 64);
    __shared__ double wsum[4];
    const int lane = threadIdx.x & 63, wid = threadIdx.x >> 6;
    if (lane == 0) wsum[wid] = s;
    __syncthreads();
    if (threadIdx.x == 0)
        slots[dst] = wsum[0] + wsum[1] + wsum[2] + wsum[3];
}

// prev0 -> f16 + per-row sums; block 0 also zeroes the gate slots.
__global__ __launch_bounds__(256)
void prev0_prep_k(const float* __restrict__ prev0, ushort* __restrict__ P_h,
                  float* __restrict__ prevsum0, double* __restrict__ slots)
{
    const int b = blockIdx.x, tid = threadIdx.x;
    if (b == 0 && tid < 16) slots[tid] = 0.0;
    const size_t ro = (size_t)b * H_;
    const float4 v = ((const float4*)(prev0 + ro))[tid];
    ushort4 h;
    h.x = f2h(v.x); h.y = f2h(v.y); h.z = f2h(v.z); h.w = f2h(v.w);
    ((ushort4*)(P_h + ro))[tid] = h;
    float sm = v.x + v.y + v.z + v.w;
#pragma unroll
    for (int off = 32; off > 0; off >>= 1) sm += __shfl_down(sm, off, 64);
    __shared__ float w2[4];
    const int lane = tid & 63, wid = tid >> 6;
    if (lane == 0) w2[wid] = sm;
    __syncthreads();
    if (tid == 0) prevsum0[b] = w2[0] + w2[1] + w2[2] + w2[3];
}

// Wr -> f16 (blocks 0..1023); Wout -> f16 + transposed f16 (blocks 1024..1535)
__global__ __launch_bounds__(256)
void conv_w_k(const float* __restrict__ Wr, ushort* __restrict__ Wr_h,
              const float* __restrict__ Wout, ushort* __restrict__ W_h,
              ushort* __restrict__ WT_h)
{
    const int bid = blockIdx.x;
    if (bid < 1024) {
        const size_t i = (size_t)bid * 256 + threadIdx.x;
        const float4 v = ((const float4*)Wr)[i];
        ushort4 h;
        h.x = f2h(v.x); h.y = f2h(v.y); h.z = f2h(v.z); h.w = f2h(v.w);
        ((ushort4*)Wr_h)[i] = h;
    } else {
        const int idx = (bid - 1024) * 256 + threadIdx.x;   // < NOBS*H_
        const ushort h = f2h(Wout[idx]);
        W_h[idx] = h;
        const int o = idx >> 10, hh = idx & 1023;
        WT_h[(size_t)hh * NOBS + o] = h;
    }
}

__global__ __launch_bounds__(256)
void copy_k(const float* __restrict__ src, float* __restrict__ dst)
{
    const size_t i = (size_t)blockIdx.x * 256 + threadIdx.x;
    ((float4*)dst)[i] = ((const float4*)src)[i];
}

// ---------------------------------------------------------------------------
extern "C" void kernel_launch(void* const* d_in, const int* in_sizes, int n_in,
                              void* d_out, int out_size, void* d_ws, size_t ws_size,
                              hipStream_t stream)
{
    const int*   dirs  = (const int*)d_in[0];
    const int*   obs   = (const int*)d_in[1];
    const float* Wr    = (const float*)d_in[2];
    const float* Win   = (const float*)d_in[3];
    const float* Wout  = (const float*)d_in[4];
    const float* prev0 = (const float*)d_in[5];
    float* out = (float*)d_out;

    const size_t SZ = (size_t)B_ * H_;
    double* slots    = (double*)d_ws;                       // 16 doubles
    double* rowpart  = slots + 16;                          // B_ doubles
    float*  C        = (float*)(rowpart + B_);
    float*  T        = C + SZ;
    float*  part     = T + SZ;                              // KS_*B_*NOBS
    float*  prevsum0 = part + (size_t)KS_ * B_ * NOBS;
    float*  rowsum   = prevsum0 + B_;
    ushort* Wr_h     = (ushort*)(rowsum + B_);
    ushort* W_h      = Wr_h + (size_t)H_ * H_;
    ushort* WT_h     = W_h + (size_t)NOBS * H_;
    ushort* C_h      = WT_h + (size_t)H_ * NOBS;
    ushort* P_h      = C_h + SZ;
    ushort* J_h      = P_h + SZ;

    const dim3 blk(256);
    const dim3 gBig(H_ / 64, B_ / 64);     // 16 x 64 = 1024 blocks
    const dim3 gLog(KS_, B_ / 64);         //  8 x 64 =  512 blocks

    prev0_prep_k<<<B_, blk, 0, stream>>>(prev0, P_h, prevsum0, slots);
    conv_w_k<<<1024 + 512, blk, 0, stream>>>(Wr, Wr_h, Wout, W_h, WT_h);

    // initial: T = relu(Wr@prev0 + drive); C = norm(T); slot[0]
    gemm_f16_k<0, 64><<<gBig, blk, 0, stream>>>(
        P_h, H_, Wr_h, H_, T, dirs, Win, nullptr, slots, -1);
    normadv_k<false><<<B_, blk, 0, stream>>>(
        T, C, C_h, nullptr, prevsum0, rowsum, rowpart, slots, -1);
    slot_fin_k<<<1, blk, 0, stream>>>(rowpart, slots, 0, -1);

    for (int it = 0; it < MAXIT; ++it) {
        // R = relu(Wr@prev + drive) -> T.  At it==0, T already holds R_0.
        if (it > 0)
            gemm_f16_k<0, 64><<<gBig, blk, 0, stream>>>(
                P_h, H_, Wr_h, H_, T, dirs, Win, nullptr, slots, it);
        // logits split-K partials from cur
        gemm_f16_k<1, 128><<<gLog, blk, 0, stream>>>(
            C_h, H_, W_h, H_, part, nullptr, nullptr, nullptr, slots, it);
        // reduce + softmax + Jv (f16)
        softjv_k<0><<<B_ / 4, blk, 0, stream>>>(part, obs, J_h, nullptr, slots, it);
        // T = C + lr*((T - C) + Jv @ Wout)
        gemm_f16_k<2, 64><<<gBig, blk, 0, stream>>>(
            J_h, NOBS, WT_h, NOBS, T, nullptr, nullptr, C, slots, it);
        // prev <- cur; C <- norm(T); slot[it+1]
        normadv_k<true><<<B_, blk, 0, stream>>>(
            T, C, C_h, P_h, rowsum, rowsum, rowpart, slots, it);
        slot_fin_k<<<1, blk, 0, stream>>>(rowpart, slots, it + 1, it);
    }

    // outputs: softmax(Wout @ cur), then cur
    gemm_f16_k<1, 128><<<gLog, blk, 0, stream>>>(
        C_h, H_, W_h, H_, part, nullptr, nullptr, nullptr, slots, -1);
    softjv_k<1><<<B_ / 4, blk, 0, stream>>>(part, obs, nullptr, out, slots, -1);
    copy_k<<<SZ / 4 / 256, blk, 0, stream>>>(C, out + (size_t)B_ * NOBS);
}